// Round 2
// baseline (72700.372 us; speedup 1.0000x reference)
//
#include <hip/hip_runtime.h>

#define HH    100
#define G4    400      // 4*H
#define LSEQ  168
#define STEPS 48
#define NTICK 8066     // ticks 0..8065 (L0 at tick t, L1 at tick t-1)
#define NPOOL 176      // row-units streamed from L2 instead of registers
#define KPAD  112      // padded K so every pool quarter is 28 wide

__device__ __forceinline__ float sigmoidf_(float x) {
    return 1.0f / (1.0f + __expf(-x));
}
__device__ __forceinline__ float tanhf_(float x) {
    return 1.0f - 2.0f / (__expf(2.0f * x) + 1.0f);
}

// Pool weights, transposed: wsT[k*NPOOL + u], k in [0,112) (k>=100 zero-padded).
// u <  16 : W_hh0 row 384+u   -> gate0 row 384+u      (input h0)
// u < 32  : W_ih1 row 368+u   -> gate1 row 368+u (A)  (input h0)
// u < 176 : W_hh1 row 224+u   -> gate1 row 224+u (B)  (input h1)
__global__ void prep_kernel(const float* __restrict__ Whh0,
                            const float* __restrict__ Wih1,
                            const float* __restrict__ Whh1,
                            float* __restrict__ wsT) {
    int i = blockIdx.x * 256 + threadIdx.x;
    if (i >= KPAD * NPOOL) return;
    int k = i / NPOOL, u = i % NPOOL;
    float v = 0.0f;
    if (k < HH) {
        if (u < 16)       v = Whh0[(384 + u) * HH + k];
        else if (u < 32)  v = Wih1[(368 + u) * HH + k];
        else              v = Whh1[(224 + u) * HH + k];
    }
    wsT[i] = v;
}

// 2 waves/EU exactly: 8-wave WG, 1 WG/CU, 256-VGPR budget for the allocator.
// (R1's __launch_bounds__(512,2) let the backend pick a 128-reg/4-wave target
//  and spill the 200-float weight arrays -> 6.2 GB of scratch traffic.)
__global__
__attribute__((amdgpu_flat_work_group_size(512, 512), amdgpu_waves_per_eu(2, 2)))
void lstm_kernel(const float* __restrict__ X,     // (512,168)
                 const float* __restrict__ Wih0,  // (400,1)
                 const float* __restrict__ Whh0,  // (400,100)
                 const float* __restrict__ bih0,
                 const float* __restrict__ bhh0,
                 const float* __restrict__ Wih1,  // (400,100)
                 const float* __restrict__ Whh1,  // (400,100)
                 const float* __restrict__ bih1,
                 const float* __restrict__ bhh1,
                 const float* __restrict__ fcw,   // (100)
                 const float* __restrict__ fcb,   // (1)
                 const float* __restrict__ wsT,   // (112,176)
                 float* __restrict__ out)         // (512,48)
{
    __shared__ __align__(16) float sh0[2][KPAD];   // h of layer0, per batch
    __shared__ __align__(16) float sh1[2][KPAD];   // h of layer1
    __shared__ float g0s[2][G4];                   // W_hh0 . h0 partials (rows 0..383)
    __shared__ float g1a[2][G4];                   // W_ih1 . h0 partials (rows 0..383)
    __shared__ float g1b[2][256];                  // W_hh1 . h1 partials (rows 0..255)
    __shared__ float pp[2][NPOOL][5];              // pool quarter partials (stride 5: bank-conflict-free)
    __shared__ float sbias0[G4], sbias1[G4], swih0[G4], sfcw[HH];
    __shared__ float yacc[2], ybuf[2];

    const int t  = threadIdx.x;
    const int wg = blockIdx.x;
    const int b0 = wg * 2, b1 = wg * 2 + 1;

    // ---- one-time init ----
    for (int i = t; i < 2 * KPAD; i += 512) {
        ((float*)sh0)[i] = 0.0f;
        ((float*)sh1)[i] = 0.0f;
    }
    if (t < G4) {
        sbias0[t] = bih0[t] + bhh0[t];
        sbias1[t] = bih1[t] + bhh1[t];
        swih0[t]  = Wih0[t];
    }
    if (t < HH) sfcw[t] = fcw[t];
    if (t == 0) { yacc[0] = yacc[1] = 0.0f; ybuf[0] = ybuf[1] = 0.0f; }
    const float fcb0 = fcb[0];

    // register-resident weights: two K=100 row-units per thread
    float w0[HH], w1[HH];
    {
        const float *p0, *p1;
        if (t < 384) { p0 = Whh0 + t * HH;         p1 = Wih1 + t * HH; }
        else         { p0 = Whh1 + (t - 384) * HH; p1 = Whh1 + (t - 256) * HH; }
        #pragma unroll
        for (int k = 0; k < HH; k += 4) {
            float4 a = *(const float4*)(p0 + k);
            w0[k] = a.x; w0[k+1] = a.y; w0[k+2] = a.z; w0[k+3] = a.w;
            float4 b = *(const float4*)(p1 + k);
            w1[k] = b.x; w1[k+1] = b.y; w1[k+2] = b.z; w1[k+3] = b.w;
        }
    }

    // main-FMA input vector (wave-uniform): waves 0..5 read h0, waves 6..7 read h1
    const float* hin = (t < 384) ? &sh0[0][0] : &sh1[0][0];

    // pool task params (quarter 1 = q=t; quarter 2 = q=512+t for t<192)
    const int u1 = t % NPOOL, kq1 = t / NPOOL;
    const int u2 = (160 + t) % NPOOL, kq2 = (512 + t) / NPOOL;
    const bool has2 = (t < 192);
    const float* hq1 = (u1 < 32) ? &sh0[0][0] : &sh1[0][0];
    const float* hq2 = (u2 < 32) ? &sh0[0][0] : &sh1[0][0];
    const float* wp1 = wsT + kq1 * 28 * NPOOL + u1;
    const float* wp2 = wsT + kq2 * 28 * NPOOL + u2;
    const int k01 = kq1 * 28, k02 = kq2 * 28;

    // cell-update params
    float c0 = 0.0f, c1 = 0.0f;
    const int ub = (t < 200) ? (t / 100) : ((t - 200) / 100);
    const int uj = (t < 200) ? (t % 100) : ((t - 200) % 100);
    const float* xrow = X + ((ub == 0) ? b0 : b1) * LSEQ;

    __syncthreads();

    #pragma unroll 1
    for (int tick = 0; tick < NTICK; ++tick) {
        const bool ydtick = (tick >= 2) && ((tick - 2) % LSEQ == LSEQ - 1);

        // ================= Phase A: all FMA work =================
        {
            float a00 = 0.f, a01 = 0.f, a10 = 0.f, a11 = 0.f;
            #pragma unroll
            for (int kc = 0; kc < 25; ++kc) {
                const float4 ha = *(const float4*)(hin + 4 * kc);
                const float4 hb = *(const float4*)(hin + KPAD + 4 * kc);
                const float w00 = w0[4*kc], w01 = w0[4*kc+1], w02 = w0[4*kc+2], w03 = w0[4*kc+3];
                const float w10 = w1[4*kc], w11 = w1[4*kc+1], w12 = w1[4*kc+2], w13 = w1[4*kc+3];
                a00 += w00*ha.x; a01 += w00*hb.x; a10 += w10*ha.x; a11 += w10*hb.x;
                a00 += w01*ha.y; a01 += w01*hb.y; a10 += w11*ha.y; a11 += w11*hb.y;
                a00 += w02*ha.z; a01 += w02*hb.z; a10 += w12*ha.z; a11 += w12*hb.z;
                a00 += w03*ha.w; a01 += w03*hb.w; a10 += w13*ha.w; a11 += w13*hb.w;
            }
            if (t < 384) {
                g0s[0][t] = a00; g0s[1][t] = a01;
                g1a[0][t] = a10; g1a[1][t] = a11;
            } else {
                const int r1 = t - 384, r2 = t - 256;
                g1b[0][r1] = a00; g1b[1][r1] = a01;
                g1b[0][r2] = a10; g1b[1][r2] = a11;
            }
        }
        // pool quarters (weights stream from L2, coalesced per-k)
        {
            float pa = 0.f, pb = 0.f;
            #pragma unroll
            for (int i = 0; i < 28; i += 4) {
                const float4 hA = *(const float4*)(hq1 + k01 + i);
                const float4 hB = *(const float4*)(hq1 + KPAD + k01 + i);
                const float wa = wp1[(i+0)*NPOOL], wb = wp1[(i+1)*NPOOL];
                const float wc = wp1[(i+2)*NPOOL], wd = wp1[(i+3)*NPOOL];
                pa += wa*hA.x + wb*hA.y + wc*hA.z + wd*hA.w;
                pb += wa*hB.x + wb*hB.y + wc*hB.z + wd*hB.w;
            }
            pp[0][u1][kq1] = pa; pp[1][u1][kq1] = pb;
            if (has2) {
                float qa = 0.f, qb = 0.f;
                #pragma unroll
                for (int i = 0; i < 28; i += 4) {
                    const float4 hA = *(const float4*)(hq2 + k02 + i);
                    const float4 hB = *(const float4*)(hq2 + KPAD + k02 + i);
                    const float wa = wp2[(i+0)*NPOOL], wb = wp2[(i+1)*NPOOL];
                    const float wc = wp2[(i+2)*NPOOL], wd = wp2[(i+3)*NPOOL];
                    qa += wa*hA.x + wb*hA.y + wc*hA.z + wd*hA.w;
                    qb += wa*hB.x + wb*hB.y + wc*hB.z + wd*hB.w;
                }
                pp[0][u2][kq2] = qa; pp[1][u2][kq2] = qb;
            }
        }
        // fc dot (rare: once per 168 ticks), reads stable h1
        if (ydtick && t < 200) {
            atomicAdd(&yacc[ub], sfcw[uj] * sh1[ub][uj]);
        }
        __syncthreads();

        // ================= Phase B: cell updates =================
        if (t < 200) {
            if (tick < 8064) {           // L0 processes global step g0 = tick
                const int s = tick / LSEQ, p = tick % LSEQ;
                float x;
                if (s == 0)            x = xrow[p];
                else if (p < LSEQ - 1) x = xrow[p + 1];
                else                   x = ybuf[ub];
                const int j = uj, b = ub;
                const int ro = 300 + j;
                float Gi = sbias0[j]       + swih0[j]       * x + g0s[b][j];
                float Gf = sbias0[100 + j] + swih0[100 + j] * x + g0s[b][100 + j];
                float Gg = sbias0[200 + j] + swih0[200 + j] * x + g0s[b][200 + j];
                float po = (ro < 384) ? g0s[b][ro]
                                      : (pp[b][ro-384][0] + pp[b][ro-384][1] +
                                         pp[b][ro-384][2] + pp[b][ro-384][3]);
                float Go = sbias0[ro] + swih0[ro] * x + po;
                c0 = sigmoidf_(Gf) * c0 + sigmoidf_(Gi) * tanhf_(Gg);
                sh0[b][j] = sigmoidf_(Go) * tanhf_(c0);
            }
        } else if (t < 400) {
            if (tick >= 1 && tick <= 8064) {   // L1 processes g1 = tick-1
                const int j = uj, b = ub;
                const int rg = 200 + j, ro = 300 + j;
                float Gi = sbias1[j]       + g1a[b][j]       + g1b[b][j];
                float Gf = sbias1[100 + j] + g1a[b][100 + j] + g1b[b][100 + j];
                float Bg = (rg < 256) ? g1b[b][rg]
                                      : (pp[b][rg-224][0] + pp[b][rg-224][1] +
                                         pp[b][rg-224][2] + pp[b][rg-224][3]);
                float Gg = sbias1[rg] + g1a[b][rg] + Bg;
                float Ao = (ro < 384) ? g1a[b][ro]
                                      : (pp[b][ro-368][0] + pp[b][ro-368][1] +
                                         pp[b][ro-368][2] + pp[b][ro-368][3]);
                float Bo = pp[b][ro-224][0] + pp[b][ro-224][1] +
                           pp[b][ro-224][2] + pp[b][ro-224][3];
                float Go = sbias1[ro] + Ao + Bo;
                c1 = sigmoidf_(Gf) * c1 + sigmoidf_(Gi) * tanhf_(Gg);
                sh1[b][j] = sigmoidf_(Go) * tanhf_(c1);
            }
        } else if (t == 400) {
            if (ydtick) {                 // finalize y for chunk s
                const int s = (tick - 2) / LSEQ;
                float y0 = yacc[0] + fcb0;
                float y1 = yacc[1] + fcb0;
                ybuf[0] = y0; ybuf[1] = y1;
                out[b0 * STEPS + s] = y0;
                out[b1 * STEPS + s] = y1;
                yacc[0] = 0.0f; yacc[1] = 0.0f;
            }
        }
        __syncthreads();
    }
}

extern "C" void kernel_launch(void* const* d_in, const int* in_sizes, int n_in,
                              void* d_out, int out_size, void* d_ws, size_t ws_size,
                              hipStream_t stream) {
    const float* X    = (const float*)d_in[0];
    const float* Wih0 = (const float*)d_in[1];
    const float* Whh0 = (const float*)d_in[2];
    const float* bih0 = (const float*)d_in[3];
    const float* bhh0 = (const float*)d_in[4];
    const float* Wih1 = (const float*)d_in[5];
    const float* Whh1 = (const float*)d_in[6];
    const float* bih1 = (const float*)d_in[7];
    const float* bhh1 = (const float*)d_in[8];
    const float* fcw  = (const float*)d_in[9];
    const float* fcb  = (const float*)d_in[10];
    float* out = (float*)d_out;
    float* wsT = (float*)d_ws;   // 112*176 floats = 78,848 B of scratch

    hipLaunchKernelGGL(prep_kernel, dim3((KPAD * NPOOL + 255) / 256), dim3(256), 0, stream,
                       Whh0, Wih1, Whh1, wsT);
    hipLaunchKernelGGL(lstm_kernel, dim3(256), dim3(512), 0, stream,
                       X, Wih0, Whh0, bih0, bhh0, Wih1, Whh1, bih1, bhh1,
                       fcw, fcb, wsT, out);
}

// Round 3
// 49448.352 us; speedup vs baseline: 1.4702x; 1.4702x over previous
//
#include <hip/hip_runtime.h>

#define HH    100
#define G4    400
#define LSEQ  168
#define STEPS 48
#define NTICK 8066     // L0 at tick t (t<8064), L1 at tick t-1
#define NPOOL 176      // Whh1 rows 224..399 streamed from L2
#define SHP   112      // padded h stride (zeros beyond 100)

__device__ __forceinline__ float sigmoidf_(float x) {
    return 1.0f / (1.0f + __expf(-x));
}
__device__ __forceinline__ float tanhf_(float x) {
    return 1.0f - 2.0f / (__expf(2.0f * x) + 1.0f);
}

// Pool weights packed for coalesced dwordx4: index ((q*7+i)*NPOOL+u)*4+c <-> k=28q+4i+c
// value = Whh1[(224+u)*100 + k], zero-padded for k>=100.
__global__ void prep_kernel(const float* __restrict__ Whh1, float* __restrict__ wsT) {
    int idx = blockIdx.x * 256 + threadIdx.x;
    if (idx >= SHP * NPOOL) return;
    int k = idx / NPOOL, u = idx % NPOOL;
    int q = k / 28, r = k % 28, i = r / 4, c = r % 4;
    float v = (k < HH) ? Whh1[(224 + u) * HH + k] : 0.0f;
    wsT[((q * 7 + i) * NPOOL + u) * 4 + c] = v;
}

// 1024 threads = 16 waves = forced 4 waves/SIMD -> natural 128-VGPR budget.
// Unit map (thread t owns one K=100 row-unit):
//   t <  400 : Whh0 row t        (input h0)  -> L0 gate partial
//   t <  800 : Wih1 row t-400    (input h0)  -> L1 "a" partial
//   t < 1024 : Whh1 row t-800    (input h1)  -> L1 "b" partial (rows 0..223)
// Pool (threads 320..1023, one quarter each): Whh1 rows 224..399 from L2.
__global__
__attribute__((amdgpu_flat_work_group_size(1024, 1024), amdgpu_waves_per_eu(4, 4)))
void lstm_kernel(const float* __restrict__ X,     // (512,168)
                 const float* __restrict__ Wih0,  // (400,1)
                 const float* __restrict__ Whh0,  // (400,100)
                 const float* __restrict__ bih0,
                 const float* __restrict__ bhh0,
                 const float* __restrict__ Wih1,  // (400,100)
                 const float* __restrict__ Whh1,  // (400,100)
                 const float* __restrict__ bih1,
                 const float* __restrict__ bhh1,
                 const float* __restrict__ fcw,   // (100)
                 const float* __restrict__ fcb,   // (1)
                 const float* __restrict__ wsT,   // pool, packed
                 float* __restrict__ out)         // (512,48)
{
    __shared__ __align__(16) float shs[2][2][SHP];   // [layer][batch][k], pad zeros
    __shared__ __align__(16) float4 wlds[2][1024];   // weight chunks 23,24 per unit
    __shared__ float gAll[2][1024];                  // per-batch unit partials
    __shared__ float pp[2][NPOOL][5];                // pool partials (stride 5)
    __shared__ float sb0[G4], sb1[G4], sw0[G4], sfcw[HH];
    __shared__ float yacc[2], ybuf[2];

    const int t  = threadIdx.x;
    const int wg = blockIdx.x;
    const int b0 = wg * 2;

    // ---- one-time init ----
    for (int i = t; i < 2 * 2 * SHP; i += 1024) ((float*)shs)[i] = 0.0f;
    if (t < G4) {
        sb0[t] = bih0[t] + bhh0[t];
        sb1[t] = bih1[t] + bhh1[t];
        sw0[t] = Wih0[t];
    }
    if (t < HH) sfcw[t] = fcw[t];
    if (t == 0) { yacc[0] = yacc[1] = 0.0f; ybuf[0] = ybuf[1] = 0.0f; }
    const float fcb0 = fcb[0];

    // ---- register-resident weights: 92 floats (23 float4 chunks) ----
    const float* wrow = (t < 400) ? (Whh0 + t * HH)
                      : (t < 800) ? (Wih1 + (t - 400) * HH)
                                  : (Whh1 + (t - 800) * HH);
    float wv[92];
    #pragma unroll
    for (int j = 0; j < 23; ++j) {
        float4 a = ((const float4*)wrow)[j];
        wv[4*j] = a.x; wv[4*j+1] = a.y; wv[4*j+2] = a.z; wv[4*j+3] = a.w;
    }
    // Pin in VGPRs: opaque asm outputs cannot be rematerialized as reloads.
    #pragma unroll
    for (int j = 0; j < 92; j += 4)
        asm volatile("" : "+v"(wv[j]), "+v"(wv[j+1]), "+v"(wv[j+2]), "+v"(wv[j+3]));
    // chunks 23,24 live in LDS
    wlds[0][t] = ((const float4*)wrow)[23];
    wlds[1][t] = ((const float4*)wrow)[24];

    // main-FMA input vector (h0 for units <800, h1 for the rest)
    const float* hin = (t < 800) ? &shs[0][0][0] : &shs[1][0][0];

    // pool task (threads 320..1023): unit u, quarter q
    const int tau = t - 320;
    const bool haspool = (t >= 320);
    const int pu = tau % NPOOL, pq = tau / NPOOL;
    const float* wp = wsT + ((pq * 7) * NPOOL + pu) * 4;
    const int hk0 = 28 * pq;

    // cell-update params
    float c0 = 0.0f, c1 = 0.0f;
    const int ub = (t < 200) ? (t / 100) : ((t - 200) / 100);
    const int uj = (t < 200) ? (t % 100) : ((t - 200) % 100);
    const float* xrow = X + (b0 + ub) * LSEQ;

    __syncthreads();

    #pragma unroll 1
    for (int tick = 0; tick < NTICK; ++tick) {
        const bool ydtick = (tick >= 2) && ((tick - 2) % LSEQ == LSEQ - 1);

        // ================= Phase A: all FMA work =================
        {
            float a0 = 0.f, a1 = 0.f;
            #pragma unroll
            for (int kc = 0; kc < 23; ++kc) {
                const float4 hA = *(const float4*)(hin + 4 * kc);
                const float4 hB = *(const float4*)(hin + SHP + 4 * kc);
                a0 += wv[4*kc]*hA.x + wv[4*kc+1]*hA.y + wv[4*kc+2]*hA.z + wv[4*kc+3]*hA.w;
                a1 += wv[4*kc]*hB.x + wv[4*kc+1]*hB.y + wv[4*kc+2]*hB.z + wv[4*kc+3]*hB.w;
            }
            #pragma unroll
            for (int e = 0; e < 2; ++e) {
                const float4 w4 = wlds[e][t];
                const float4 hA = *(const float4*)(hin + 92 + 4 * e);
                const float4 hB = *(const float4*)(hin + SHP + 92 + 4 * e);
                a0 += w4.x*hA.x + w4.y*hA.y + w4.z*hA.z + w4.w*hA.w;
                a1 += w4.x*hB.x + w4.y*hB.y + w4.z*hB.z + w4.w*hB.w;
            }
            gAll[0][t] = a0; gAll[1][t] = a1;
        }
        if (haspool) {
            float pa = 0.f, pb = 0.f;
            #pragma unroll
            for (int i = 0; i < 7; ++i) {
                const float4 w4 = *(const float4*)(wp + i * NPOOL * 4);
                const float4 hA = *(const float4*)(&shs[1][0][hk0 + 4 * i]);
                const float4 hB = *(const float4*)(&shs[1][1][hk0 + 4 * i]);
                pa += w4.x*hA.x + w4.y*hA.y + w4.z*hA.z + w4.w*hA.w;
                pb += w4.x*hB.x + w4.y*hB.y + w4.z*hB.z + w4.w*hB.w;
            }
            pp[0][pu][pq] = pa; pp[1][pu][pq] = pb;
        }
        if (ydtick && t < 200) {
            atomicAdd(&yacc[ub], sfcw[uj] * shs[1][ub][uj]);
        }
        __syncthreads();

        // ================= Phase B: cell updates =================
        if (t < 200) {
            if (tick < 8064) {               // L0, global step g0 = tick
                const int s = tick / LSEQ, p = tick % LSEQ;
                float x;
                if (s == 0)            x = xrow[p];
                else if (p < LSEQ - 1) x = xrow[p + 1];
                else                   x = ybuf[ub];
                const int j = uj, b = ub;
                float Gi = sb0[j]       + sw0[j]       * x + gAll[b][j];
                float Gf = sb0[100 + j] + sw0[100 + j] * x + gAll[b][100 + j];
                float Gg = sb0[200 + j] + sw0[200 + j] * x + gAll[b][200 + j];
                float Go = sb0[300 + j] + sw0[300 + j] * x + gAll[b][300 + j];
                c0 = sigmoidf_(Gf) * c0 + sigmoidf_(Gi) * tanhf_(Gg);
                shs[0][b][j] = sigmoidf_(Go) * tanhf_(c0);
            }
        } else if (t < 400) {
            if (tick >= 1 && tick <= 8064) { // L1, global step g1 = tick-1
                const int j = uj, b = ub;
                // partial(r) = Wih1 part + Whh1 part
                float Gi = sb1[j]       + gAll[b][400 + j]       + gAll[b][800 + j];
                float Gf = sb1[100 + j] + gAll[b][500 + j]       + gAll[b][900 + j];
                float bg = (j < 24) ? gAll[b][1000 + j]
                                    : (pp[b][j - 24][0] + pp[b][j - 24][1] +
                                       pp[b][j - 24][2] + pp[b][j - 24][3]);
                float Gg = sb1[200 + j] + gAll[b][600 + j] + bg;
                float bo = pp[b][76 + j][0] + pp[b][76 + j][1] +
                           pp[b][76 + j][2] + pp[b][76 + j][3];
                float Go = sb1[300 + j] + gAll[b][700 + j] + bo;
                c1 = sigmoidf_(Gf) * c1 + sigmoidf_(Gi) * tanhf_(Gg);
                shs[1][b][j] = sigmoidf_(Go) * tanhf_(c1);
            }
        } else if (t == 1023) {
            if (ydtick) {
                const int s = (tick - 2) / LSEQ;
                float y0 = yacc[0] + fcb0;
                float y1 = yacc[1] + fcb0;
                ybuf[0] = y0; ybuf[1] = y1;
                out[b0 * STEPS + s]       = y0;
                out[(b0 + 1) * STEPS + s] = y1;
                yacc[0] = 0.0f; yacc[1] = 0.0f;
            }
        }
        __syncthreads();
    }
}

extern "C" void kernel_launch(void* const* d_in, const int* in_sizes, int n_in,
                              void* d_out, int out_size, void* d_ws, size_t ws_size,
                              hipStream_t stream) {
    const float* X    = (const float*)d_in[0];
    const float* Wih0 = (const float*)d_in[1];
    const float* Whh0 = (const float*)d_in[2];
    const float* bih0 = (const float*)d_in[3];
    const float* bhh0 = (const float*)d_in[4];
    const float* Wih1 = (const float*)d_in[5];
    const float* Whh1 = (const float*)d_in[6];
    const float* bih1 = (const float*)d_in[7];
    const float* bhh1 = (const float*)d_in[8];
    const float* fcw  = (const float*)d_in[9];
    const float* fcb  = (const float*)d_in[10];
    float* out = (float*)d_out;
    float* wsT = (float*)d_ws;   // 112*176 floats = 78,848 B

    hipLaunchKernelGGL(prep_kernel, dim3((SHP * NPOOL + 255) / 256), dim3(256), 0, stream,
                       Whh1, wsT);
    hipLaunchKernelGGL(lstm_kernel, dim3(256), dim3(1024), 0, stream,
                       X, Wih0, Whh0, bih0, bhh0, Wih1, Whh1, bih1, bhh1,
                       fcw, fcb, wsT, out);
}